// Round 11
// baseline (426.032 us; speedup 1.0000x reference)
//
#include <hip/hip_runtime.h>
#include <hip/hip_bf16.h>

// Round 16: kill the qkv VALU tail (qkv was 149us @ VALUBusy 44%, MfmaUtil 30%).
// (1) RoPE cos/sin table: sincosf(s*inv) with s up to 2047 rad does full
//     Payne-Hanek range reduction (~50-100 VALU ops) x32 per thread — the
//     epilogue VALU matched the whole main loop. rope_table kernel computes
//     (cos,sin) once per (s,d2) -> 512KB float2 table, L2-resident; epilogue
//     does two 8B loads per (ti,r). Value-identical.
// (2) V epilogue writes f16 [M][HID] (f16->f32->f16 through v_split LDS is
//     lossless): vb 32->16MB write, v_split read 32->16MB. Value-identical.
// attn / oproj / quant_all unchanged from round 15.

typedef _Float16 f16;
typedef _Float16 f16x8 __attribute__((ext_vector_type(8)));
typedef float f32x4 __attribute__((ext_vector_type(4)));

static constexpr int Bd = 2, Sd = 2048, NH = 32, HD = 64, HID = 2048;
static constexpr int Md = Bd * Sd;   // 4096
static constexpr int LSTR = 72;      // LDS row stride (f16) for K/V attn tiles
static constexpr int PSTR = 68;      // LDS row stride (f16) for P tile

// ---------------- FP4 fake-quant (E2M1, block-16 absmax) ----------------
__device__ __forceinline__ float fp4_grid_round(float ay) {
  if (ay <= 0.25f) return 0.0f;
  if (ay <= 0.75f) return 0.5f;
  if (ay <= 1.25f) return 1.0f;
  if (ay <= 1.75f) return 1.5f;
  if (ay <= 2.5f)  return 2.0f;
  if (ay <= 3.5f)  return 3.0f;
  if (ay <= 5.0f)  return 4.0f;
  return 6.0f;
}

// ---------------- RoPE table: T[s*32+d2] = (cos, sin) of s*inv(d2) ----------
__global__ __launch_bounds__(256) void rope_table(float2* __restrict__ T) {
  int idx = blockIdx.x * 256 + threadIdx.x;   // 65536 = 2048*32
  int s = idx >> 5, d2 = idx & 31;
  float inv = expf(-0.2878231366242557f * (float)d2);  // ln(1e4)/32
  float sn, cs;
  sincosf((float)s * inv, &sn, &cs);
  T[idx] = make_float2(cs, sn);
}

// Fused quant of x + Wq + Wk + Wv + Wo in one launch; all hi-only (f16 trunc).
__global__ __launch_bounds__(256) void quant_all(
    const float* __restrict__ x,  const float* __restrict__ Wq,
    const float* __restrict__ Wk, const float* __restrict__ Wv,
    const float* __restrict__ Wo,
    f16* __restrict__ xh,  f16* __restrict__ wqh,
    f16* __restrict__ wkh, f16* __restrict__ wvh,
    f16* __restrict__ woh) {
  constexpr int NXB = (Md * HID / 4) / 256;   // 8192 blocks for x
  constexpr int NWB = (HID * HID / 4) / 256;  // 4096 blocks per weight
  const int blk = blockIdx.x;
  const float* in; f16* hi; int base;
  if (blk < NXB)            { in = x;  hi = xh;  base = 0; }
  else if (blk < NXB + NWB) { in = Wq; hi = wqh; base = NXB; }
  else if (blk < NXB+2*NWB) { in = Wk; hi = wkh; base = NXB + NWB; }
  else if (blk < NXB+3*NWB) { in = Wv; hi = wvh; base = NXB + 2*NWB; }
  else                      { in = Wo; hi = woh; base = NXB + 3*NWB; }
  const int t = (blk - base) * 256 + threadIdx.x;
  float v[4];
#pragma unroll
  for (int i = 0; i < 4; ++i) v[i] = in[4 * t + i];
  float a = fmaxf(fmaxf(fabsf(v[0]), fabsf(v[1])), fmaxf(fabsf(v[2]), fabsf(v[3])));
  a = fmaxf(a, __shfl_xor(a, 1));
  a = fmaxf(a, __shfl_xor(a, 2));
  float scale = (a == 0.0f) ? 1.0f : (a / 6.0f);
#pragma unroll
  for (int i = 0; i < 4; ++i) {
    float y = v[i] / scale;
    float g = fp4_grid_round(fabsf(y));
    float qv = copysignf(g * scale, y);
    hi[4 * t + i] = (f16)qv;   // round-to-nearest f16, err <= 2^-11 rel
  }
}

// ---------------- async global->LDS helper ----------------------------------
__device__ __forceinline__ void gl2lds16(const f16* g, f16* l) {
  __builtin_amdgcn_global_load_lds(
      (const __attribute__((address_space(1))) unsigned int*)g,
      (__attribute__((address_space(3))) unsigned int*)l, 16, 0, 0);
}

// ---------------- single-pass GEMM core (double-buffered LDS) ---------------
// 256 thr = 4 waves (2x2), 128x128 tile, BK=32.
#define GEMM128_BODY1(Ah, Bh, Kk, IM, JN)                                      \
  __shared__ f16 sAh[2][128 * 32];                                             \
  __shared__ f16 sBhb[2][128 * 32];                                            \
  const int tid = threadIdx.x;                                                 \
  const int w = tid >> 6, lane = tid & 63;                                     \
  const int wm = w & 1, wn = w >> 1;                                           \
  const int quad = lane >> 4, n16 = lane & 15;                                 \
  const int im = (IM), jn = (JN);                                              \
  const int srow = lane >> 2;                                                  \
  const int schk = (lane & 3) * 8;                                             \
  const size_t arow0 = (size_t)(im * 128) * Kk;                                \
  const size_t brow0 = (size_t)(jn * 128) * Kk;                                \
  f32x4 acc[4][4];                                                             \
  _Pragma("unroll") for (int i = 0; i < 4; ++i)                                \
      _Pragma("unroll") for (int j = 0; j < 4; ++j)                            \
          acc[i][j] = f32x4{0.f, 0.f, 0.f, 0.f};                               \
  _Pragma("unroll") for (int g = 0; g < 2; ++g) {                              \
    int r = g * 64 + w * 16;                                                   \
    int lb = r * 32;                                                           \
    size_t go = (size_t)(r + srow) * Kk + schk;                                \
    gl2lds16(Ah + arow0 + go, &sAh[0][lb]);                                    \
    gl2lds16(Bh + brow0 + go, &sBhb[0][lb]);                                   \
  }                                                                            \
  __syncthreads();                                                             \
  for (int kk = 0; kk < Kk; kk += 32) {                                        \
    const int db = (kk >> 5) & 1;                                              \
    if (kk + 32 < Kk) {                                                        \
      const int nb = db ^ 1;                                                   \
      _Pragma("unroll") for (int g = 0; g < 2; ++g) {                          \
        int r = g * 64 + w * 16;                                               \
        int lb = r * 32;                                                       \
        size_t go = (size_t)(r + srow) * Kk + kk + 32 + schk;                  \
        gl2lds16(Ah + arow0 + go, &sAh[nb][lb]);                               \
        gl2lds16(Bh + brow0 + go, &sBhb[nb][lb]);                              \
      }                                                                        \
    }                                                                          \
    f16x8 ah[4], bh[4];                                                        \
    _Pragma("unroll") for (int t = 0; t < 4; ++t) {                            \
      int ao = (wm * 64 + t * 16 + n16) * 32 + quad * 8;                       \
      int bo = (wn * 64 + t * 16 + n16) * 32 + quad * 8;                       \
      ah[t] = *(const f16x8*)&sAh[db][ao];                                     \
      bh[t] = *(const f16x8*)&sBhb[db][bo];                                    \
    }                                                                          \
    _Pragma("unroll") for (int ti = 0; ti < 4; ++ti)                           \
        _Pragma("unroll") for (int tj = 0; tj < 4; ++tj)                       \
      acc[ti][tj] = __builtin_amdgcn_mfma_f32_16x16x32_f16(ah[ti], bh[tj],     \
                                                           acc[ti][tj], 0, 0, 0); \
    __syncthreads();                                                           \
  }

// Fused QKV GEMM (single-pass): blockIdx.y in [0,16)=Q (RoPE epi), [16,32)=K
// (RoPE epi), [32,48)=V (f16 epi into Vh [M][HID]).
__global__ __launch_bounds__(256) void gemm128_qkv(
    const f16* __restrict__ Xh,
    const f16* __restrict__ Wqh, const f16* __restrict__ Wkh,
    const f16* __restrict__ Wvh, const float2* __restrict__ T,
    f16* __restrict__ Qoh, f16* __restrict__ Koh,
    f16* __restrict__ Vh) {
  const int sel = blockIdx.y >> 4;  // 0=Q 1=K 2=V (block-uniform)
  const f16* Bhp = (sel == 0) ? Wqh : (sel == 1) ? Wkh : Wvh;
  GEMM128_BODY1(Xh, Bhp, HID, (int)blockIdx.x, ((int)blockIdx.y & 15))
  if (sel == 2) {
    // f16 epilogue into Vh [M, HID] (truncation; lossless through v_split)
#pragma unroll
    for (int ti = 0; ti < 4; ++ti)
#pragma unroll
      for (int tj = 0; tj < 4; ++tj) {
        size_t row = (size_t)(im * 128 + wm * 64 + ti * 16 + quad * 4);
        size_t col = jn * 128 + wn * 64 + tj * 16 + n16;
#pragma unroll
        for (int r = 0; r < 4; ++r)
          Vh[(row + r) * HID + col] = (f16)acc[ti][tj][r];
      }
  } else {
    // fused RoPE (table) + qscale, f16 truncation, head-major [head][s][d]
    // Q qscale folds log2(e): softmax uses exp2 directly (m=0 softmax).
    f16* Oh = sel ? Koh : Qoh;
    const float qscale = sel ? 1.0f : 0.18033688011112042f;  // 0.125*log2(e)
    const int hidx = (jn * 128 + wn * 64) >> 6;  // 0..31
    const int b = im >> 4;
    const size_t obase = (size_t)(b * 32 + hidx) * Sd * 64;
#pragma unroll
    for (int ti = 0; ti < 4; ++ti)
#pragma unroll
      for (int r = 0; r < 4; ++r) {
        int row = im * 128 + wm * 64 + ti * 16 + quad * 4 + r;
        int s = row & (Sd - 1);
        float2 t0 = T[s * 32 + n16];        // d2 = n16       (tjp=0)
        float2 t1 = T[s * 32 + 16 + n16];   // d2 = 16 + n16  (tjp=1)
        float x1, x2, o1, o2;
        size_t i0 = obase + (size_t)s * 64 + n16;
        // tjp = 0: d = n16, d+32
        x1 = acc[ti][0][r] * qscale;  x2 = acc[ti][2][r] * qscale;
        o1 = x1 * t0.x - x2 * t0.y;   o2 = x2 * t0.x + x1 * t0.y;
        Oh[i0] = (f16)o1;             Oh[i0 + 32] = (f16)o2;
        // tjp = 1: d = 16+n16, d+32
        x1 = acc[ti][1][r] * qscale;  x2 = acc[ti][3][r] * qscale;
        o1 = x1 * t1.x - x2 * t1.y;   o2 = x2 * t1.x + x1 * t1.y;
        Oh[i0 + 16] = (f16)o1;        Oh[i0 + 48] = (f16)o2;
      }
  }
}

// Single-pass f16 GEMM for the output projection (never re-quantized).
__global__ __launch_bounds__(256) void gemm128_h(const f16* __restrict__ Ah,
                                                 const f16* __restrict__ Bh,
                                                 float* __restrict__ C,
                                                 int Nn, int Kk) {
  GEMM128_BODY1(Ah, Bh, Kk, (int)blockIdx.x, (int)blockIdx.y)
#pragma unroll
  for (int ti = 0; ti < 4; ++ti)
#pragma unroll
    for (int tj = 0; tj < 4; ++tj) {
      size_t row = (size_t)(im * 128 + wm * 64 + ti * 16 + quad * 4);
      size_t col = jn * 128 + wn * 64 + tj * 16 + n16;
#pragma unroll
      for (int r = 0; r < 4; ++r)
        C[(row + r) * Nn + col] = acc[ti][tj][r];
    }
}

// ---------------- V transpose (f16 in/out): Vt[head][d][s] ------------------
__global__ __launch_bounds__(256) void v_split_t_kernel(const f16* __restrict__ V,
                                                        f16* __restrict__ Vth) {
  __shared__ float tile[64][65];
  int head = blockIdx.x;
  int st = blockIdx.y;
  int b = head >> 5, h = head & 31;
  int tid = threadIdx.x;
  int r = tid >> 2, c4 = (tid & 3) * 16;
  const f16* vp = V + ((size_t)(b * Sd + st * 64 + r)) * HID + h * 64 + c4;
#pragma unroll
  for (int i = 0; i < 16; i += 8) {
    f16x8 v = *(const f16x8*)(vp + i);
#pragma unroll
    for (int j = 0; j < 8; ++j) tile[r][c4 + i + j] = (float)v[j];
  }
  __syncthreads();
  int d = tid >> 2, s0 = (tid & 3) * 16;
  f16x8 hv[2];
#pragma unroll
  for (int g = 0; g < 2; ++g)
#pragma unroll
    for (int i = 0; i < 8; ++i)
      hv[g][i] = (f16)tile[s0 + g * 8 + i][d];
  size_t outb = (size_t)head * 64 * Sd + (size_t)d * Sd + st * 64 + s0;
  *(f16x8*)(Vth + outb) = hv[0];
  *(f16x8*)(Vth + outb + 8) = hv[1];
}

// ---------------- MFMA flash attention, 128 q-rows per block ----------------
// 4 waves x 32 q-rows; K/V tiles of 64; Q/K/V single-f16; P f16.
// m=0 softmax (scores bounded; shift-invariant): P = 2^(S'), S' = S*log2e
// via Q-side qscale fold. Denominator accumulated lane-locally, reduced once
// in epilogue. True T14 barriers (lgkmcnt-only). Epilogue: fused fp4-quant.
__global__ __launch_bounds__(256) void attn_mfma_kernel(
    const f16* __restrict__ Qh, const f16* __restrict__ Kh,
    const f16* __restrict__ Vth, f16* __restrict__ Ohq) {
  __shared__ f16 lds_kh[64 * LSTR];
  __shared__ f16 lds_vh[64 * LSTR];
  __shared__ f16 lds_ph[128 * PSTR];   // 4 waves * 32 rows

  const int tid = threadIdx.x;
  const int wave = tid >> 6, lane = tid & 63;
  const int quad = lane >> 4, n16 = lane & 15;
  const int head = blockIdx.x;
  const int qt = 15 - blockIdx.y;        // longest blocks first (global LPT)
  const int b = head >> 5, h = head & 31;

  const size_t hbase = (size_t)head * Sd * 64;
  const size_t vbase = (size_t)head * 64 * Sd;
  const int qrow_w = qt * 128 + wave * 32;

  // persistent Q fragments (A-layout), 2 row-tiles of 16
  f16x8 qah[2][2];
#pragma unroll
  for (int ti = 0; ti < 2; ++ti) {
    const f16* qp = Qh + hbase + (size_t)(qrow_w + ti * 16 + n16) * 64 + quad * 8;
    qah[ti][0] = *(const f16x8*)(qp);
    qah[ti][1] = *(const f16x8*)(qp + 32);
  }

  f32x4 acco[2][4];
#pragma unroll
  for (int ti = 0; ti < 2; ++ti)
#pragma unroll
    for (int t = 0; t < 4; ++t) acco[ti][t] = f32x4{0.f, 0.f, 0.f, 0.f};
  // lane-local denominator partials (cols == n16 mod 16); reduced in epilogue
  float lsum[2][4];
#pragma unroll
  for (int ti = 0; ti < 2; ++ti)
#pragma unroll
    for (int r = 0; r < 4; ++r) lsum[ti][r] = 0.f;

  const int sr = tid >> 2, ss = (tid & 3) * 16;
  const int nkt = 2 * qt + 2;

  const f16* pk = Kh  + hbase + (size_t)sr * 64 + ss;
  const f16* pv = Vth + vbase + (size_t)sr * Sd + ss;

  f16x8 r0, r1, r4, r5;
#define ISSUE_KV(ktv) {                                                        \
    const f16* gk = pk + (size_t)(ktv) * (64 * 64);                            \
    const f16* gv = pv + (ktv) * 64;                                           \
    r0 = *(const f16x8*)(gk);  r1 = *(const f16x8*)(gk + 8);                   \
    r4 = *(const f16x8*)(gv);  r5 = *(const f16x8*)(gv + 8); }

  // lgkmcnt-only barrier: register-destined global prefetch flies across.
#define LDS_BARRIER() __asm__ volatile("s_waitcnt lgkmcnt(0)\n\ts_barrier" ::: "memory")

  ISSUE_KV(0);

  for (int kt = 0; kt < nkt; ++kt) {
    LDS_BARRIER();
    {
      int la = sr * LSTR + ss;
      *(f16x8*)&lds_kh[la] = r0; *(f16x8*)&lds_kh[la + 8] = r1;
      *(f16x8*)&lds_vh[la] = r4; *(f16x8*)&lds_vh[la + 8] = r5;
    }
    if (kt + 1 < nkt) ISSUE_KV(kt + 1);
    LDS_BARRIER();

    if (kt * 64 > qrow_w + 31) continue;

    f32x4 sacc[2][4];
#pragma unroll
    for (int ti = 0; ti < 2; ++ti)
#pragma unroll
      for (int t = 0; t < 4; ++t) sacc[ti][t] = f32x4{0.f, 0.f, 0.f, 0.f};
#pragma unroll
    for (int t = 0; t < 4; ++t) {
      int off = (t * 16 + n16) * LSTR + quad * 8;
      f16x8 kb0 = *(const f16x8*)&lds_kh[off];
      f16x8 kb1 = *(const f16x8*)&lds_kh[off + 32];
#pragma unroll
      for (int ti = 0; ti < 2; ++ti) {
        sacc[ti][t] = __builtin_amdgcn_mfma_f32_16x16x32_f16(qah[ti][0], kb0, sacc[ti][t], 0, 0, 0);
        sacc[ti][t] = __builtin_amdgcn_mfma_f32_16x16x32_f16(qah[ti][1], kb1, sacc[ti][t], 0, 0, 0);
      }
    }

    if (kt * 64 + 63 > qrow_w) {  // partial (diagonal) tile mask
#pragma unroll
      for (int ti = 0; ti < 2; ++ti)
#pragma unroll
        for (int t = 0; t < 4; ++t)
#pragma unroll
          for (int r = 0; r < 4; ++r) {
            int kc = kt * 64 + t * 16 + n16;
            int qr = qrow_w + ti * 16 + quad * 4 + r;
            if (kc > qr) sacc[ti][t][r] = -INFINITY;
          }
    }

    // m=0 softmax numerator: P = 2^(S'); lane-local denominator partials.
#pragma unroll
    for (int ti = 0; ti < 2; ++ti)
#pragma unroll
      for (int t = 0; t < 4; ++t)
#pragma unroll
        for (int r = 0; r < 4; ++r) {
          float p = exp2f(sacc[ti][t][r]);   // bare v_exp_f32; 2^-inf = 0
          lsum[ti][r] += p;
          int addr = (wave * 32 + ti * 16 + quad * 4 + r) * PSTR + t * 16 + n16;
          lds_ph[addr] = (f16)p;
        }

    __asm__ volatile("s_waitcnt lgkmcnt(0)" ::: "memory");

    // O += P * V
    f16x8 pa0[2], pa1[2];
#pragma unroll
    for (int ti = 0; ti < 2; ++ti) {
      int pbase = (wave * 32 + ti * 16 + n16) * PSTR + quad * 8;
      pa0[ti] = *(const f16x8*)&lds_ph[pbase];
      pa1[ti] = *(const f16x8*)&lds_ph[pbase + 32];
    }
#pragma unroll
    for (int t = 0; t < 4; ++t) {
      int off = (t * 16 + n16) * LSTR + quad * 8;
      f16x8 vb0 = *(const f16x8*)&lds_vh[off];
      f16x8 vb1 = *(const f16x8*)&lds_vh[off + 32];
#pragma unroll
      for (int ti = 0; ti < 2; ++ti) {
        acco[ti][t] = __builtin_amdgcn_mfma_f32_16x16x32_f16(pa0[ti], vb0, acco[ti][t], 0, 0, 0);
        acco[ti][t] = __builtin_amdgcn_mfma_f32_16x16x32_f16(pa1[ti], vb1, acco[ti][t], 0, 0, 0);
      }
    }
  }
#undef ISSUE_KV
#undef LDS_BARRIER

  // epilogue: reduce denominator once (16-lane tree), then fused fp4 quant
  // (block-16 = t-column across n16 lanes), exact scale + f16 truncation;
  // hi-only output [M][HID] for the O-projection.
#pragma unroll
  for (int ti = 0; ti < 2; ++ti)
#pragma unroll
    for (int i = 1; i < 16; i <<= 1)
#pragma unroll
      for (int r = 0; r < 4; ++r)
        lsum[ti][r] += __shfl_xor(lsum[ti][r], i);

#pragma unroll
  for (int ti = 0; ti < 2; ++ti) {
#pragma unroll
    for (int r = 0; r < 4; ++r) {
      float rl = 1.f / lsum[ti][r];
      int qr = qrow_w + ti * 16 + quad * 4 + r;
      float v[4], a[4];
#pragma unroll
      for (int t = 0; t < 4; ++t) { v[t] = acco[ti][t][r] * rl; a[t] = fabsf(v[t]); }
#pragma unroll
      for (int i = 1; i < 16; i <<= 1)
#pragma unroll
        for (int t = 0; t < 4; ++t) a[t] = fmaxf(a[t], __shfl_xor(a[t], i));
#pragma unroll
      for (int t = 0; t < 4; ++t) {
        float scale = (a[t] == 0.0f) ? 1.0f : (a[t] / 6.0f);
        float g = fp4_grid_round(fabsf(v[t]) / scale);
        float qv = copysignf(g * scale, v[t]);
        size_t idx = ((size_t)(b * Sd + qr)) * HID + h * 64 + t * 16 + n16;
        Ohq[idx] = (f16)qv;
      }
    }
  }
}

// ---------------- launch ----------------------------------------------------
extern "C" void kernel_launch(void* const* d_in, const int* in_sizes, int n_in,
                              void* d_out, int out_size, void* d_ws, size_t ws_size,
                              hipStream_t stream) {
  (void)in_sizes; (void)n_in; (void)out_size; (void)ws_size;
  const float* x  = (const float*)d_in[0];
  const float* Wq = (const float*)d_in[1];
  const float* Wk = (const float*)d_in[2];
  const float* Wv = (const float*)d_in[3];
  const float* Wo = (const float*)d_in[4];
  float* out = (float*)d_out;

  const size_t NX = (size_t)Md * HID;   // 8,388,608
  const size_t NW = (size_t)HID * HID;  // 4,194,304

  char* w = (char*)d_ws;
  size_t off = 0;
  auto alloc = [&](size_t bytes) { void* p = w + off; off += (bytes + 255) & ~(size_t)255; return p; };
  f16* xh  = (f16*)alloc(NX * 2);
  f16* wqh = (f16*)alloc(NW * 2);   // wqh+wkh contiguous (16MB): reused as oh
  f16* wkh = (f16*)alloc(NW * 2);
  f16* wvh = (f16*)alloc(NW * 2);
  f16* woh = (f16*)alloc(NW * 2);
  f16* vbh = (f16*)alloc(NX * 2);   // V in [M][HID] f16
  f16* qhs = (f16*)alloc(NX * 2);
  f16* khs = (f16*)alloc(NX * 2);
  float2* rt = (float2*)alloc((size_t)Sd * 32 * sizeof(float2));  // 512 KB
  // aliases (dead-after analysis):
  f16* vth = xh;   // x quant dead after qkv GEMM; v_split_t runs after it
  f16* oh  = wqh;  // wq+wk quants dead after qkv GEMM; oh spans both (NX*2 B)

  constexpr int NXB = (int)((size_t)Md * HID / 4 / 256);   // 8192
  constexpr int NWB = (int)((size_t)HID * HID / 4 / 256);  // 4096
  rope_table<<<(Sd * 32) / 256, 256, 0, stream>>>(rt);
  quant_all<<<NXB + 4 * NWB, 256, 0, stream>>>(
      x, Wq, Wk, Wv, Wo, xh, wqh, wkh, wvh, woh);

  // fused Q/K/V projection GEMM (single-pass) + table-RoPE: grid (32, 48)
  gemm128_qkv<<<dim3(Md / 128, 48), 256, 0, stream>>>(
      xh, wqh, wkh, wvh, rt, qhs, khs, vbh);

  v_split_t_kernel<<<dim3(64, 32), 256, 0, stream>>>(vbh, vth);

  // attention + fused fp4-quant of O (hi-only, exact scale + truncation)
  attn_mfma_kernel<<<dim3(64, 16), 256, 0, stream>>>(qhs, khs, vth, oh);

  // single-pass f16 output projection (result never re-quantized)
  gemm128_h<<<dim3(Md / 128, HID / 128), 256, 0, stream>>>(oh, woh, out, HID, HID);
}